// Round 4
// baseline (211.860 us; speedup 1.0000x reference)
//
#include <hip/hip_runtime.h>

// Problem constants (fixed by setup_inputs)
constexpr int B = 4, N = 2048, I = 256, H = 4, D = 64, E = 256; // E = H*D
constexpr float LOG2E = 1.44269504088896340736f;

typedef __bf16 bf16x8 __attribute__((ext_vector_type(8)));
typedef float f32x4 __attribute__((ext_vector_type(4)));
typedef unsigned short us8 __attribute__((ext_vector_type(8)));

__device__ __forceinline__ unsigned short f2bf(float f) {
    unsigned u = __builtin_bit_cast(unsigned, f);
    u = (u + 0x7FFFu + ((u >> 16) & 1u)) >> 16;  // RNE
    return (unsigned short)u;
}

// ---------------- Kernel 1: per-head projection + H1/H2 (log2-scaled) + HpT(bf16) ----------------
// HpT[b][h][d][n] = bf16( sum_i X[b][n][i] * W[h][i][d] )
// H1[b][h][n] = LOG2E * dot(Hp, a[h,0:D]);  H2 with a[h,D:2D]
constexpr int NT = 8; // nodes per block

__global__ __launch_bounds__(256) void k_proj(const float* __restrict__ X,
                                              const float* __restrict__ W,
                                              const float* __restrict__ a,
                                              unsigned short* __restrict__ HpT,
                                              float* __restrict__ H1,
                                              float* __restrict__ H2) {
    int blk = blockIdx.x;
    int b = blk / (N / NT);
    int n0 = (blk % (N / NT)) * NT;
    int t = threadIdx.x;
    int h = t >> 6, d = t & 63;

    __shared__ float Xs[NT][I]; // 8 KB

    const float4* Xr = (const float4*)(X + ((size_t)b * N + n0) * I);
    #pragma unroll
    for (int k = 0; k < (NT * I / 4) / 256; ++k) { // 2 iters
        int v = t + 256 * k;
        ((float4*)&Xs[0][0])[v] = Xr[v];
    }
    __syncthreads();

    float acc[NT];
    #pragma unroll
    for (int nn = 0; nn < NT; ++nn) acc[nn] = 0.f;

    const float* Wp = W + (size_t)h * I * D + d;
    #pragma unroll 2
    for (int i4 = 0; i4 < I; i4 += 4) {
        float w0 = Wp[(size_t)(i4 + 0) * D];
        float w1 = Wp[(size_t)(i4 + 1) * D];
        float w2 = Wp[(size_t)(i4 + 2) * D];
        float w3 = Wp[(size_t)(i4 + 3) * D];
        #pragma unroll
        for (int nn = 0; nn < NT; ++nn) {
            float4 x = *(const float4*)&Xs[nn][i4];
            acc[nn] += x.x * w0 + x.y * w1 + x.z * w2 + x.w * w3;
        }
    }

    float a1 = a[h * (2 * D) + d];
    float a2 = a[h * (2 * D) + D + d];

    #pragma unroll
    for (int nn = 0; nn < NT; ++nn) {
        float v1 = acc[nn] * a1;
        float v2 = acc[nn] * a2;
        #pragma unroll
        for (int off = 32; off > 0; off >>= 1) {
            v1 += __shfl_down(v1, off, 64);
            v2 += __shfl_down(v2, off, 64);
        }
        if (d == 0) {
            H1[(size_t)(b * H + h) * N + (n0 + nn)] = v1 * LOG2E;
            H2[(size_t)(b * H + h) * N + (n0 + nn)] = v2 * LOG2E;
        }
    }

    // transposed bf16 store: 8 consecutive n per thread at row d
    us8 o;
    #pragma unroll
    for (int nn = 0; nn < NT; ++nn) o[nn] = f2bf(acc[nn]);
    *(us8*)&HpT[((size_t)(b * H + h) * D + d) * N + n0] = o;
}

// ---------------- Kernel 2: fused softmax-agg + LDS reduce + output GEMM ----------------
// Block = (b, i-tile of 16 rows). 8 waves; wave w covers j in [w*256, (w+1)*256).
// Lane l owns A-frag slots (row=l&15, k=(l>>4)*8+e), computes the 4-head softmax
// once per pair in registers; 16 MFMAs (4 heads x 4 d-tiles) per 32-j step.
// Then: LDS tree-reduce the 8 waves' acc; one i-tile = 16 COMPLETE rows of the
// reshaped R (row n' = h*512 + i/4 mixes only this tile's i-rows), so the block
// finishes with the 16x256 @ 256x256 out-GEMM. No partial buffers, no k_out.
constexpr int NSPL = 8;
constexpr int JRANGE = N / NSPL;    // 256
constexpr int NSTEP = JRANGE / 32;  // 8

__global__ __launch_bounds__(512, 4) void k_agg(const int* __restrict__ A,
                                                const float* __restrict__ H1,
                                                const float* __restrict__ H2,
                                                const unsigned short* __restrict__ HpT,
                                                const float* __restrict__ Wo,
                                                const float* __restrict__ bo,
                                                float* __restrict__ out) {
    __shared__ __align__(16) char smem[65536]; // red[4][64][64] f32 overlay, later Rs+WT
    float* red = (float*)smem;

    int bid = blockIdx.x;
    int it = bid & (N / 16 - 1); // 0..127
    int b  = bid >> 7;
    int i0 = it * 16;
    int t = threadIdx.x;
    int wv = t >> 6, l = t & 63;
    int row = l & 15;  // A-frag row / B-frag col
    int kg  = l >> 4;  // k-chunk: k = kg*8 + e
    int jb  = wv * JRANGE;

    float h1v[H];
    #pragma unroll
    for (int h = 0; h < H; ++h) h1v[h] = H1[(size_t)(b * H + h) * N + i0 + row];

    f32x4 acc[H][4] = {}; // [head][d-tile]

    const int4* Ar = (const int4*)(A + (size_t)b * N * N + (size_t)(i0 + row) * N + jb + kg * 8);
    const float* H2b = H2 + (size_t)b * H * N + jb + kg * 8;
    const unsigned short* Hpb = HpT + (size_t)(b * H) * D * N;

    #pragma unroll 2
    for (int s = 0; s < NSTEP; ++s) {
        // ---- loads for this step ----
        int4 a0 = Ar[s * 8];
        int4 a1 = Ar[s * 8 + 1];
        float4 h2lo[H], h2hi[H];
        #pragma unroll
        for (int h = 0; h < H; ++h) {
            const float4* hp = (const float4*)(H2b + (size_t)h * N) + s * 8;
            h2lo[h] = hp[0];
            h2hi[h] = hp[1];
        }

        // ---- softmax for 8 pairs, all 4 heads, registers only ----
        bf16x8 af[H];
        #pragma unroll
        for (int e = 0; e < 8; ++e) {
            int aij = (e < 4) ? ((const int*)&a0)[e] : ((const int*)&a1)[e - 4];
            bool on = aij > 0;
            float v0 = h1v[0] + ((e < 4) ? ((const float*)&h2lo[0])[e] : ((const float*)&h2hi[0])[e - 4]);
            float v1 = h1v[1] + ((e < 4) ? ((const float*)&h2lo[1])[e] : ((const float*)&h2hi[1])[e - 4]);
            float v2 = h1v[2] + ((e < 4) ? ((const float*)&h2lo[2])[e] : ((const float*)&h2hi[2])[e - 4]);
            float v3 = h1v[3] + ((e < 4) ? ((const float*)&h2lo[3])[e] : ((const float*)&h2hi[3])[e - 4]);
            // leaky-relu in log2 domain; mask to 0 (exp2(0)=1 -> w=0.25 exact)
            float s0 = on ? fmaxf(v0, 0.2f * v0) : 0.f;
            float s1 = on ? fmaxf(v1, 0.2f * v1) : 0.f;
            float s2 = on ? fmaxf(v2, 0.2f * v2) : 0.f;
            float s3 = on ? fmaxf(v3, 0.2f * v3) : 0.f;
            // no max-subtraction: |s| <= ~30 in log2 domain, exp2 stays finite
            float e0 = exp2f(s0);
            float e1 = exp2f(s1);
            float e2 = exp2f(s2);
            float e3 = exp2f(s3);
            float zi = __builtin_amdgcn_rcpf(e0 + e1 + e2 + e3);
            af[0][e] = (__bf16)(e0 * zi);
            af[1][e] = (__bf16)(e1 * zi);
            af[2][e] = (__bf16)(e2 * zi);
            af[3][e] = (__bf16)(e3 * zi);
        }

        // ---- MFMA: 4 heads x 4 d-tiles ----
        #pragma unroll
        for (int h = 0; h < H; ++h) {
            #pragma unroll
            for (int nt = 0; nt < 4; ++nt) {
                const us8* bp = (const us8*)(Hpb + ((size_t)h * D + row + 16 * nt) * N + jb + kg * 8 + s * 32);
                bf16x8 bfr = __builtin_bit_cast(bf16x8, bp[0]);
                acc[h][nt] = __builtin_amdgcn_mfma_f32_16x16x32_bf16(af[h], bfr, acc[h][nt], 0, 0, 0);
            }
        }
    }

    // ---- LDS tree-reduce across the 8 waves; red layout [slot][q][lane] (conflict-free) ----
    #define DUMP(slot)                                                        \
        {   _Pragma("unroll") for (int h = 0; h < H; ++h)                     \
            _Pragma("unroll") for (int nt = 0; nt < 4; ++nt)                  \
            _Pragma("unroll") for (int r = 0; r < 4; ++r)                     \
                red[(slot) * 4096 + ((h * 4 + nt) * 4 + r) * 64 + l] = acc[h][nt][r]; }
    #define TAKE(slot)                                                        \
        {   _Pragma("unroll") for (int h = 0; h < H; ++h)                     \
            _Pragma("unroll") for (int nt = 0; nt < 4; ++nt)                  \
            _Pragma("unroll") for (int r = 0; r < 4; ++r)                     \
                acc[h][nt][r] += red[(slot) * 4096 + ((h * 4 + nt) * 4 + r) * 64 + l]; }

    if (wv >= 4) DUMP(wv - 4);
    __syncthreads();
    if (wv < 4) TAKE(wv);
    __syncthreads();
    if (wv == 2 || wv == 3) DUMP(wv - 2);
    __syncthreads();
    if (wv < 2) TAKE(wv);
    __syncthreads();
    if (wv == 1) DUMP(2);
    __syncthreads();

    // Rs occupies slot0/1 region (0..16KB); wave 0 reads slot 2 (32..48KB) - disjoint
    float* Rs = (float*)smem;                              // [16][E]
    float (*WT)[E + 1] = (float(*)[E + 1])(smem + 16384);  // 32 x 257 f32

    if (wv == 0) {
        TAKE(2);
        // R-row mapping: i = kg*4+r -> a=kg, c=r; Rs[h*4+kg][r*64 + (l&15) + 16*nt]
        #pragma unroll
        for (int h = 0; h < H; ++h)
            #pragma unroll
            for (int nt = 0; nt < 4; ++nt)
                #pragma unroll
                for (int r = 0; r < 4; ++r)
                    Rs[(size_t)(h * 4 + kg) * E + r * 64 + row + 16 * nt] = acc[h][nt][r];
    }
    __syncthreads();

    // ---- output GEMM: out[16 rows] = Rs @ Wo^T + bo ----
    int e = t & 255;
    int rh = t >> 8; // 0/1 -> rows rh*8 .. rh*8+7
    float acc8[8];
    float bias = bo[e];
    #pragma unroll
    for (int i = 0; i < 8; ++i) acc8[i] = bias;

    int c_l = t & 31, rb = t >> 5; // staging coords
    for (int et = 0; et < E / 32; ++et) { // 8 tiles of contraction dim
        #pragma unroll
        for (int k = 0; k < 16; ++k) {
            int r = rb + 16 * k;
            WT[c_l][r] = Wo[(size_t)r * E + et * 32 + c_l]; // WT[c'][r] = Wo[r][et*32+c']
        }
        __syncthreads();
        #pragma unroll
        for (int cg = 0; cg < 8; ++cg) {
            float w0 = WT[cg * 4 + 0][e];
            float w1 = WT[cg * 4 + 1][e];
            float w2 = WT[cg * 4 + 2][e];
            float w3 = WT[cg * 4 + 3][e];
            #pragma unroll
            for (int i = 0; i < 8; ++i) {
                float4 rv = *(const float4*)&Rs[(size_t)(rh * 8 + i) * E + et * 32 + cg * 4];
                acc8[i] += rv.x * w0 + rv.y * w1 + rv.z * w2 + rv.w * w3;
            }
        }
        __syncthreads();
    }

    #pragma unroll
    for (int i = 0; i < 8; ++i) {
        int r2 = rh * 8 + i;
        int hh = r2 >> 2, aa = r2 & 3;
        int nloc = hh * 512 + it * 4 + aa; // reshape: row n' = h*512 + i/4
        out[((size_t)b * N + nloc) * E + e] = acc8[i];
    }
}

extern "C" void kernel_launch(void* const* d_in, const int* in_sizes, int n_in,
                              void* d_out, int out_size, void* d_ws, size_t ws_size,
                              hipStream_t stream) {
    const float* X  = (const float*)d_in[0];
    const int*   A  = (const int*)d_in[1];
    const float* W  = (const float*)d_in[2];
    const float* a  = (const float*)d_in[3];
    const float* Wo = (const float*)d_in[4];
    const float* bo = (const float*)d_in[5];
    float* out = (float*)d_out;

    unsigned short* HpT = (unsigned short*)d_ws;             // B*H*D*N bf16 = 4.2 MB
    float* H1 = (float*)(HpT + (size_t)B * H * D * N);       // 32768 floats
    float* H2 = H1 + B * H * N;                              // 32768 floats

    k_proj<<<dim3(B * N / NT), dim3(256), 0, stream>>>(X, W, a, HpT, H1, H2);
    k_agg<<<dim3(B * (N / 16)), dim3(512), 0, stream>>>(A, H1, H2, HpT, Wo, bo, out);
}

// Round 6
// 206.866 us; speedup vs baseline: 1.0241x; 1.0241x over previous
//
#include <hip/hip_runtime.h>

// Problem constants (fixed by setup_inputs)
constexpr int B = 4, N = 2048, I = 256, H = 4, D = 64, E = 256; // E = H*D
constexpr float LOG2E = 1.44269504088896340736f;

typedef __bf16 bf16x8 __attribute__((ext_vector_type(8)));
typedef float f32x4 __attribute__((ext_vector_type(4)));
typedef unsigned short us8 __attribute__((ext_vector_type(8)));

__device__ __forceinline__ unsigned short f2bf(float f) {
    unsigned u = __builtin_bit_cast(unsigned, f);
    u = (u + 0x7FFFu + ((u >> 16) & 1u)) >> 16;  // RNE
    return (unsigned short)u;
}
__device__ __forceinline__ float bf2f(unsigned short s) {
    return __builtin_bit_cast(float, (unsigned)s << 16);
}

// ---------------- Kernel 1: per-head projection + H1/H2 (log2-scaled) + HpT(bf16) ----------------
// HpT[b][h][d][n] = bf16( sum_i X[b][n][i] * W[h][i][d] )
// H1[b][h][n] = LOG2E * dot(Hp, a[h,0:D]);  H2 with a[h,D:2D]
constexpr int NT = 8; // nodes per block

__global__ __launch_bounds__(256) void k_proj(const float* __restrict__ X,
                                              const float* __restrict__ W,
                                              const float* __restrict__ a,
                                              unsigned short* __restrict__ HpT,
                                              float* __restrict__ H1,
                                              float* __restrict__ H2) {
    int blk = blockIdx.x;
    int b = blk / (N / NT);
    int n0 = (blk % (N / NT)) * NT;
    int t = threadIdx.x;
    int h = t >> 6, d = t & 63;

    __shared__ float Xs[NT][I]; // 8 KB

    const float4* Xr = (const float4*)(X + ((size_t)b * N + n0) * I);
    #pragma unroll
    for (int k = 0; k < (NT * I / 4) / 256; ++k) { // 2 iters
        int v = t + 256 * k;
        ((float4*)&Xs[0][0])[v] = Xr[v];
    }
    __syncthreads();

    float acc[NT];
    #pragma unroll
    for (int nn = 0; nn < NT; ++nn) acc[nn] = 0.f;

    const float* Wp = W + (size_t)h * I * D + d;
    #pragma unroll 2
    for (int i4 = 0; i4 < I; i4 += 4) {
        float w0 = Wp[(size_t)(i4 + 0) * D];
        float w1 = Wp[(size_t)(i4 + 1) * D];
        float w2 = Wp[(size_t)(i4 + 2) * D];
        float w3 = Wp[(size_t)(i4 + 3) * D];
        #pragma unroll
        for (int nn = 0; nn < NT; ++nn) {
            float4 x = *(const float4*)&Xs[nn][i4];
            acc[nn] += x.x * w0 + x.y * w1 + x.z * w2 + x.w * w3;
        }
    }

    float a1 = a[h * (2 * D) + d];
    float a2 = a[h * (2 * D) + D + d];

    #pragma unroll
    for (int nn = 0; nn < NT; ++nn) {
        float v1 = acc[nn] * a1;
        float v2 = acc[nn] * a2;
        #pragma unroll
        for (int off = 32; off > 0; off >>= 1) {
            v1 += __shfl_down(v1, off, 64);
            v2 += __shfl_down(v2, off, 64);
        }
        if (d == 0) {
            H1[(size_t)(b * H + h) * N + (n0 + nn)] = v1 * LOG2E;
            H2[(size_t)(b * H + h) * N + (n0 + nn)] = v2 * LOG2E;
        }
    }

    // transposed bf16 store: 8 consecutive n per thread at row d
    us8 o;
    #pragma unroll
    for (int nn = 0; nn < NT; ++nn) o[nn] = f2bf(acc[nn]);
    *(us8*)&HpT[((size_t)(b * H + h) * D + d) * N + n0] = o;
}

// ---------------- Kernel 2: barrier-free per-wave head-softmax + MFMA aggregation ----------------
// 1024 blocks x 4 waves = 4096 independent waves in the main loop. Block = (jhalf, b,
// i-tile of 16); wave wv covers j in [jhalf*1024 + wv*256, +256). Lane l owns A-frag
// slots (row=l&15, k=(l>>4)*8+e); 4-head softmax once per pair in regs; 16 MFMAs
// (4 heads x 4 d-tiles) per 32-j step. Single end-of-kernel LDS reduce across the
// 4 waves -> one bf16 chunk per block (2 j-half partials globally).
constexpr int JSPL = 8;
constexpr int JRANGE = N / JSPL;    // 256
constexpr int NSTEP = JRANGE / 32;  // 8
constexpr int CH = 4096;            // u16 per (jh,b,it) chunk: 64 q-slots x 64 lanes

__global__ __launch_bounds__(256, 4) void k_agg(const int* __restrict__ A,
                                                const float* __restrict__ H1,
                                                const float* __restrict__ H2,
                                                const unsigned short* __restrict__ HpT,
                                                unsigned short* __restrict__ part) {
    __shared__ unsigned short red[4][CH]; // 32 KB

    int bid = blockIdx.x;
    int it = bid & 127;
    int b  = (bid >> 7) & 3;
    int jh = bid >> 9;           // 0/1
    int t = threadIdx.x;
    int wv = t >> 6, l = t & 63;
    int i0 = it * 16;
    int jb = jh * 1024 + wv * JRANGE;
    int row = l & 15;  // A-frag row / B-frag col
    int kg  = l >> 4;  // k-chunk: k = kg*8 + e

    float h1v[H];
    #pragma unroll
    for (int h = 0; h < H; ++h) h1v[h] = H1[(size_t)(b * H + h) * N + i0 + row];

    f32x4 acc[H][4] = {}; // [head][d-tile]

    const int4* Ar = (const int4*)(A + (size_t)b * N * N + (size_t)(i0 + row) * N + jb + kg * 8);
    const float* H2b = H2 + (size_t)b * H * N + jb + kg * 8;
    const unsigned short* Hpb = HpT + (size_t)(b * H) * D * N;

    int4 a0 = Ar[0];
    int4 a1 = Ar[1];

    #pragma unroll 2
    for (int s = 0; s < NSTEP; ++s) {
        // prefetch next step's A (clamped; scalar select)
        int sn = (s + 1 < NSTEP) ? (s + 1) : s;
        int4 na0 = Ar[sn * 8];
        int4 na1 = Ar[sn * 8 + 1];

        float4 h2lo[H], h2hi[H];
        #pragma unroll
        for (int h = 0; h < H; ++h) {
            const float4* hp = (const float4*)(H2b + (size_t)h * N) + s * 8;
            h2lo[h] = hp[0];
            h2hi[h] = hp[1];
        }

        // ---- softmax for 8 pairs, all 4 heads, registers only ----
        bf16x8 af[H];
        #pragma unroll
        for (int e = 0; e < 8; ++e) {
            int aij = (e < 4) ? ((const int*)&a0)[e] : ((const int*)&a1)[e - 4];
            bool on = aij > 0;
            float v0 = h1v[0] + ((e < 4) ? ((const float*)&h2lo[0])[e] : ((const float*)&h2hi[0])[e - 4]);
            float v1 = h1v[1] + ((e < 4) ? ((const float*)&h2lo[1])[e] : ((const float*)&h2hi[1])[e - 4]);
            float v2 = h1v[2] + ((e < 4) ? ((const float*)&h2lo[2])[e] : ((const float*)&h2hi[2])[e - 4]);
            float v3 = h1v[3] + ((e < 4) ? ((const float*)&h2lo[3])[e] : ((const float*)&h2hi[3])[e - 4]);
            // leaky-relu in log2 domain; mask score to 0 (exp2(0)=1 -> w=0.25 exact)
            float s0 = on ? fmaxf(v0, 0.2f * v0) : 0.f;
            float s1 = on ? fmaxf(v1, 0.2f * v1) : 0.f;
            float s2 = on ? fmaxf(v2, 0.2f * v2) : 0.f;
            float s3 = on ? fmaxf(v3, 0.2f * v3) : 0.f;
            // no max-subtraction: scores bounded (~2^35 max), fp32 exp2 stays finite
            float e0 = exp2f(s0);
            float e1 = exp2f(s1);
            float e2 = exp2f(s2);
            float e3 = exp2f(s3);
            float zi = __builtin_amdgcn_rcpf(e0 + e1 + e2 + e3);
            af[0][e] = (__bf16)(e0 * zi);
            af[1][e] = (__bf16)(e1 * zi);
            af[2][e] = (__bf16)(e2 * zi);
            af[3][e] = (__bf16)(e3 * zi);
        }

        // ---- MFMA: 4 heads x 4 d-tiles ----
        #pragma unroll
        for (int h = 0; h < H; ++h) {
            #pragma unroll
            for (int nt = 0; nt < 4; ++nt) {
                const us8* bp = (const us8*)(Hpb + ((size_t)h * D + row + 16 * nt) * N + jb + kg * 8 + s * 32);
                bf16x8 bfr = __builtin_bit_cast(bf16x8, bp[0]);
                acc[h][nt] = __builtin_amdgcn_mfma_f32_16x16x32_bf16(af[h], bfr, acc[h][nt], 0, 0, 0);
            }
        }

        a0 = na0;
        a1 = na1;
    }

    // ---- end-of-kernel reduce: each wave dumps bf16 to its LDS slot; sum 4 slots ----
    #pragma unroll
    for (int h = 0; h < H; ++h)
        #pragma unroll
        for (int nt = 0; nt < 4; ++nt)
            #pragma unroll
            for (int r = 0; r < 4; ++r)
                red[wv][(((h * 4 + nt) * 4 + r)) * 64 + l] = f2bf(acc[h][nt][r]);
    __syncthreads();

    unsigned short* chunk = part + (((size_t)jh * B + b) * 128 + it) * CH;
    #pragma unroll
    for (int k = 0; k < CH / 256; ++k) { // 16
        int idx = t + 256 * k;
        float s = bf2f(red[0][idx]) + bf2f(red[1][idx]) + bf2f(red[2][idx]) + bf2f(red[3][idx]);
        chunk[idx] = f2bf(s);
    }
}

// ---------------- Kernel 3: gather 2 partials -> Rs, out-GEMM, scattered row writes ----------------
__global__ __launch_bounds__(256) void k_out(const unsigned short* __restrict__ part,
                                             const float* __restrict__ Wo,
                                             const float* __restrict__ bo,
                                             float* __restrict__ out) {
    int bid = blockIdx.x;
    int it = bid & 127;
    int b  = bid >> 7;
    int t = threadIdx.x;

    __shared__ float Rs[16][E];       // 16 KB
    __shared__ float WT[32][E + 1];   // 32.9 KB

    // gather + sum the 2 bf16 partial chunks into Rs (bijective map)
    #pragma unroll
    for (int c = 0; c < 2; ++c) {
        float s8[8] = {0.f, 0.f, 0.f, 0.f, 0.f, 0.f, 0.f, 0.f};
        #pragma unroll
        for (int jh = 0; jh < 2; ++jh) {
            const unsigned short* pc = part + (((size_t)jh * B + b) * 128 + it) * CH + c * 2048 + t * 8;
            us8 raw = *(const us8*)pc;
            #pragma unroll
            for (int e = 0; e < 8; ++e) s8[e] += bf2f(raw[e]);
        }
        int q = c * 32 + (t >> 3);           // q = (h*4+nt)*4 + r
        int h = q >> 4, nt = (q >> 2) & 3, r = q & 3;
        #pragma unroll
        for (int e = 0; e < 8; ++e) {
            int l = 8 * (t & 7) + e;
            int kg = l >> 4, rw = l & 15;
            Rs[h * 4 + kg][r * 64 + rw + 16 * nt] = s8[e];
        }
    }
    __syncthreads();

    // out rows: local rr = h*4+aa -> n' = h*512 + it*4 + aa
    float acc[16];
    float bias = bo[t];
    #pragma unroll
    for (int i = 0; i < 16; ++i) acc[i] = bias;

    int c_l = t & 31, rb = t >> 5;
    for (int et = 0; et < E / 32; ++et) { // 8 contraction tiles
        #pragma unroll
        for (int k = 0; k < 32; ++k) {   // stage ALL 256 rows: r = rb + 8*k covers 0..255
            int r = rb + 8 * k;
            WT[c_l][r] = Wo[(size_t)r * E + et * 32 + c_l];
        }
        __syncthreads();
        #pragma unroll
        for (int cg = 0; cg < 8; ++cg) {
            float w0 = WT[cg * 4 + 0][t];
            float w1 = WT[cg * 4 + 1][t];
            float w2 = WT[cg * 4 + 2][t];
            float w3 = WT[cg * 4 + 3][t];
            #pragma unroll
            for (int i = 0; i < 16; ++i) {
                float4 rv = *(const float4*)&Rs[i][et * 32 + cg * 4];
                acc[i] += rv.x * w0 + rv.y * w1 + rv.z * w2 + rv.w * w3;
            }
        }
        __syncthreads();
    }

    #pragma unroll
    for (int i = 0; i < 16; ++i) {
        int hh = i >> 2, aa = i & 3;
        int nloc = hh * 512 + it * 4 + aa; // reshape: row n' = h*512 + i/4
        out[((size_t)b * N + nloc) * E + t] = acc[i];
    }
}

extern "C" void kernel_launch(void* const* d_in, const int* in_sizes, int n_in,
                              void* d_out, int out_size, void* d_ws, size_t ws_size,
                              hipStream_t stream) {
    const float* X  = (const float*)d_in[0];
    const int*   A  = (const int*)d_in[1];
    const float* W  = (const float*)d_in[2];
    const float* a  = (const float*)d_in[3];
    const float* Wo = (const float*)d_in[4];
    const float* bo = (const float*)d_in[5];
    float* out = (float*)d_out;

    // ws layout: 2 partials (2*4*128*4096 u16 = 8.4 MB), HpT (4.2 MB), H1/H2 (f32)
    unsigned short* wsu  = (unsigned short*)d_ws;
    unsigned short* part = wsu;
    unsigned short* HpT  = wsu + (size_t)2 * B * 128 * CH;
    float* H1 = (float*)(HpT + (size_t)B * H * D * N);
    float* H2 = H1 + B * H * N;

    k_proj<<<dim3(B * N / NT), dim3(256), 0, stream>>>(X, W, a, HpT, H1, H2);
    k_agg<<<dim3(2 * B * 128), dim3(256), 0, stream>>>(A, H1, H2, HpT, part);
    k_out<<<dim3(B * 128), dim3(256), 0, stream>>>(part, Wo, bo, out);
}